// Round 1
// baseline (2824.351 us; speedup 1.0000x reference)
//
#include <hip/hip_runtime.h>

#define N_NODES 100000
#define N_EDGES 1600000
#define IN_F 256
#define OUT_F 128

// ---------------- GEMM: support = x @ W  ----------------
// 16 rows per block, 128 threads (one per output column).
#define GEMM_ROWS 16

__global__ __launch_bounds__(128) void gemm_kernel(
    const float* __restrict__ x, const float* __restrict__ W,
    float* __restrict__ support)
{
    __shared__ float xs[GEMM_ROWS][IN_F];
    const int r0  = blockIdx.x * GEMM_ROWS;
    const int tid = threadIdx.x;

    // Stage 16 x-rows (16*256 floats = 4096) into LDS via float4.
    const float4* xv  = (const float4*)(x + (size_t)r0 * IN_F);
    float4*       xsv = (float4*)&xs[0][0];
    #pragma unroll
    for (int i = 0; i < (GEMM_ROWS * IN_F / 4) / 128; ++i)
        xsv[tid + i * 128] = xv[tid + i * 128];
    __syncthreads();

    float acc[GEMM_ROWS];
    #pragma unroll
    for (int r = 0; r < GEMM_ROWS; ++r) acc[r] = 0.f;

    for (int k = 0; k < IN_F; ++k) {
        const float w = W[(size_t)k * OUT_F + tid];   // coalesced across threads
        #pragma unroll
        for (int r = 0; r < GEMM_ROWS; ++r)
            acc[r] += xs[r][k] * w;                   // LDS broadcast
    }

    #pragma unroll
    for (int r = 0; r < GEMM_ROWS; ++r)
        support[(size_t)(r0 + r) * OUT_F + tid] = acc[r];
}

// ---------------- init: out[n][j] = bias[j] ----------------
__global__ __launch_bounds__(256) void init_kernel(
    float* __restrict__ out, const float* __restrict__ bias)
{
    // one float4 per thread; grid covers N_NODES*OUT_F/4 float4s
    const size_t i = (size_t)blockIdx.x * blockDim.x + threadIdx.x;
    const size_t total = (size_t)N_NODES * OUT_F / 4;
    if (i >= total) return;
    const int j4 = (int)(i & (OUT_F / 4 - 1));        // which float4 within the row
    ((float4*)out)[i] = ((const float4*)bias)[j4];
}

// ---------------- scatter: out[row] += val * support[col] ----------------
// 32 lanes per edge; each lane handles 4 features (float4 gather + 4 atomics).
__global__ __launch_bounds__(256) void scatter_kernel(
    const int* __restrict__ erow, const int* __restrict__ ecol,
    const float* __restrict__ eval, const float* __restrict__ support,
    float* __restrict__ out)
{
    const long long gid = (long long)blockIdx.x * blockDim.x + threadIdx.x;
    const long long e   = gid >> 5;
    const int lane      = (int)(gid & 31);
    if (e >= N_EDGES) return;

    const int   r = erow[e];
    const int   c = ecol[e];
    const float v = eval[e];

    const float4 s = ((const float4*)(support + (size_t)c * OUT_F))[lane];
    float* o = out + (size_t)r * OUT_F + lane * 4;
    atomicAdd(o + 0, v * s.x);
    atomicAdd(o + 1, v * s.y);
    atomicAdd(o + 2, v * s.z);
    atomicAdd(o + 3, v * s.w);
}

extern "C" void kernel_launch(void* const* d_in, const int* in_sizes, int n_in,
                              void* d_out, int out_size, void* d_ws, size_t ws_size,
                              hipStream_t stream) {
    const float* x    = (const float*)d_in[0];
    const int*   erow = (const int*)  d_in[1];
    const int*   ecol = (const int*)  d_in[2];
    const float* eval = (const float*)d_in[3];
    const float* W    = (const float*)d_in[4];
    const float* bias = (const float*)d_in[5];
    float*       out  = (float*)d_out;

    float* support = (float*)d_ws;   // N_NODES * OUT_F fp32 = 51.2 MB

    // 1) support = x @ W
    gemm_kernel<<<N_NODES / GEMM_ROWS, 128, 0, stream>>>(x, W, support);

    // 2) out = bias (broadcast) — re-initialized every launch (scatter accumulates)
    {
        const size_t total = (size_t)N_NODES * OUT_F / 4;
        init_kernel<<<(int)((total + 255) / 256), 256, 0, stream>>>(out, bias);
    }

    // 3) out[row] += val * support[col]
    {
        const long long threads = (long long)N_EDGES * 32;
        scatter_kernel<<<(int)((threads + 255) / 256), 256, 0, stream>>>(
            erow, ecol, eval, support, out);
    }
}

// Round 2
// 648.880 us; speedup vs baseline: 4.3527x; 4.3527x over previous
//
#include <hip/hip_runtime.h>

#define N_NODES 100000
#define N_EDGES 1600000
#define IN_F 256
#define OUT_F 128

// ---------------- GEMM: support = x @ W  ----------------
#define GEMM_ROWS 16

__global__ __launch_bounds__(128) void gemm_kernel(
    const float* __restrict__ x, const float* __restrict__ W,
    float* __restrict__ support)
{
    __shared__ float xs[GEMM_ROWS][IN_F];
    const int r0  = blockIdx.x * GEMM_ROWS;
    const int tid = threadIdx.x;

    const float4* xv  = (const float4*)(x + (size_t)r0 * IN_F);
    float4*       xsv = (float4*)&xs[0][0];
    #pragma unroll
    for (int i = 0; i < (GEMM_ROWS * IN_F / 4) / 128; ++i)
        xsv[tid + i * 128] = xv[tid + i * 128];
    __syncthreads();

    float acc[GEMM_ROWS];
    #pragma unroll
    for (int r = 0; r < GEMM_ROWS; ++r) acc[r] = 0.f;

    for (int k = 0; k < IN_F; ++k) {
        const float w = W[(size_t)k * OUT_F + tid];
        #pragma unroll
        for (int r = 0; r < GEMM_ROWS; ++r)
            acc[r] += xs[r][k] * w;
    }

    #pragma unroll
    for (int r = 0; r < GEMM_ROWS; ++r)
        support[(size_t)(r0 + r) * OUT_F + tid] = acc[r];
}

// ---------------- CSR build ----------------
__global__ __launch_bounds__(256) void hist_kernel(
    const int* __restrict__ erow, int* __restrict__ counts)
{
    const int e = blockIdx.x * blockDim.x + threadIdx.x;
    if (e < N_EDGES) atomicAdd(&counts[erow[e]], 1);
}

// single-block exclusive scan of counts[0..N_NODES) -> offsets[0..N_NODES]
#define SCAN_T 1024
#define SCAN_CHUNK ((N_NODES + SCAN_T - 1) / SCAN_T)

__global__ __launch_bounds__(SCAN_T) void scan_kernel(
    const int* __restrict__ counts, int* __restrict__ offsets)
{
    __shared__ int sums[SCAN_T];
    const int tid = threadIdx.x;
    const int beg = tid * SCAN_CHUNK;
    const int end = min(beg + SCAN_CHUNK, N_NODES);

    int s = 0;
    for (int i = beg; i < end; ++i) s += counts[i];
    sums[tid] = s;
    __syncthreads();

    // inclusive Hillis-Steele scan in LDS
    for (int off = 1; off < SCAN_T; off <<= 1) {
        const int v   = sums[tid];
        const int add = (tid >= off) ? sums[tid - off] : 0;
        __syncthreads();
        sums[tid] = v + add;
        __syncthreads();
    }

    int run = (tid == 0) ? 0 : sums[tid - 1];   // exclusive base for this chunk
    for (int i = beg; i < end; ++i) { offsets[i] = run; run += counts[i]; }
    if (tid == SCAN_T - 1) offsets[N_NODES] = run;
}

__global__ __launch_bounds__(256) void fill_kernel(
    const int* __restrict__ erow, const int* __restrict__ ecol,
    const float* __restrict__ eval, const int* __restrict__ offsets,
    int* __restrict__ cursor, int* __restrict__ ecol_p, float* __restrict__ eval_p)
{
    const int e = blockIdx.x * blockDim.x + threadIdx.x;
    if (e >= N_EDGES) return;
    const int r   = erow[e];
    const int pos = atomicAdd(&cursor[r], 1);
    const int dst = offsets[r] + pos;
    ecol_p[dst] = ecol[e];
    eval_p[dst] = eval[e];
}

// ---------------- SpMM: out[r] = bias + sum_e val*support[col] ----------------
__global__ __launch_bounds__(128) void spmm_kernel(
    const int* __restrict__ offsets, const int* __restrict__ ecol_p,
    const float* __restrict__ eval_p, const float* __restrict__ support,
    const float* __restrict__ bias, float* __restrict__ out)
{
    const int r   = blockIdx.x;
    const int tid = threadIdx.x;
    const int beg = offsets[r];
    const int end = offsets[r + 1];

    float acc = 0.f;
    for (int i = beg; i < end; ++i) {
        const int   c = ecol_p[i];     // uniform across block -> broadcast
        const float v = eval_p[i];
        acc += v * support[(size_t)c * OUT_F + tid];
    }
    out[(size_t)r * OUT_F + tid] = acc + bias[tid];
}

extern "C" void kernel_launch(void* const* d_in, const int* in_sizes, int n_in,
                              void* d_out, int out_size, void* d_ws, size_t ws_size,
                              hipStream_t stream) {
    const float* x    = (const float*)d_in[0];
    const int*   erow = (const int*)  d_in[1];
    const int*   ecol = (const int*)  d_in[2];
    const float* eval = (const float*)d_in[3];
    const float* W    = (const float*)d_in[4];
    const float* bias = (const float*)d_in[5];
    float*       out  = (float*)d_out;

    // workspace layout
    char* ws = (char*)d_ws;
    float* support = (float*)ws;                 ws += (size_t)N_NODES * OUT_F * 4; // 51.2 MB
    int*   counts  = (int*)ws;                   ws += (size_t)N_NODES * 4;         // 0.4 MB
    int*   offsets = (int*)ws;                   ws += (size_t)(N_NODES + 1) * 4;   // 0.4 MB
    int*   cursor  = (int*)ws;                   ws += (size_t)N_NODES * 4;         // 0.4 MB
    int*   ecol_p  = (int*)ws;                   ws += (size_t)N_EDGES * 4;         // 6.4 MB
    float* eval_p  = (float*)ws;                 ws += (size_t)N_EDGES * 4;         // 6.4 MB

    // zero counts + cursor (contiguous region? counts and cursor are separated by
    // offsets; zero them individually)
    hipMemsetAsync(counts, 0, (size_t)N_NODES * 4, stream);
    hipMemsetAsync(cursor, 0, (size_t)N_NODES * 4, stream);

    // 1) support = x @ W
    gemm_kernel<<<N_NODES / GEMM_ROWS, 128, 0, stream>>>(x, W, support);

    // 2) histogram of destination rows
    hist_kernel<<<(N_EDGES + 255) / 256, 256, 0, stream>>>(erow, counts);

    // 3) exclusive scan -> row offsets
    scan_kernel<<<1, SCAN_T, 0, stream>>>(counts, offsets);

    // 4) permute (col, val) into row-grouped order
    fill_kernel<<<(N_EDGES + 255) / 256, 256, 0, stream>>>(
        erow, ecol, eval, offsets, cursor, ecol_p, eval_p);

    // 5) segment-reduce SpMM, bias fused
    spmm_kernel<<<N_NODES, 128, 0, stream>>>(
        offsets, ecol_p, eval_p, support, bias, out);
}

// Round 3
// 407.283 us; speedup vs baseline: 6.9346x; 1.5932x over previous
//
#include <hip/hip_runtime.h>

#define N_NODES 100000
#define N_EDGES 1600000
#define IN_F 256
#define OUT_F 128

static __device__ __forceinline__ unsigned short f2bf(float f) {
    unsigned int u = __float_as_uint(f);
    unsigned int r = (u + 0x7FFFu + ((u >> 16) & 1u)) >> 16;   // RNE
    return (unsigned short)r;
}

// ---------------- GEMM: support(bf16) = x @ W  ----------------
#define GEMM_ROWS 16

__global__ __launch_bounds__(128) void gemm_kernel(
    const float* __restrict__ x, const float* __restrict__ W,
    unsigned short* __restrict__ support)
{
    __shared__ float xs[GEMM_ROWS][IN_F];
    const int r0  = blockIdx.x * GEMM_ROWS;
    const int tid = threadIdx.x;

    const float4* xv  = (const float4*)(x + (size_t)r0 * IN_F);
    float4*       xsv = (float4*)&xs[0][0];
    #pragma unroll
    for (int i = 0; i < (GEMM_ROWS * IN_F / 4) / 128; ++i)
        xsv[tid + i * 128] = xv[tid + i * 128];
    __syncthreads();

    float acc[GEMM_ROWS];
    #pragma unroll
    for (int r = 0; r < GEMM_ROWS; ++r) acc[r] = 0.f;

    for (int k = 0; k < IN_F; ++k) {
        const float w = W[(size_t)k * OUT_F + tid];
        #pragma unroll
        for (int r = 0; r < GEMM_ROWS; ++r)
            acc[r] += xs[r][k] * w;
    }

    #pragma unroll
    for (int r = 0; r < GEMM_ROWS; ++r)
        support[(size_t)(r0 + r) * OUT_F + tid] = f2bf(acc[r]);
}

// ---------------- CSR build ----------------
__global__ __launch_bounds__(256) void hist_kernel(
    const int* __restrict__ erow, int* __restrict__ counts)
{
    const int e = blockIdx.x * blockDim.x + threadIdx.x;
    if (e < N_EDGES) atomicAdd(&counts[erow[e]], 1);
}

// 3-kernel coalesced scan
#define SB 1024
#define NB ((N_NODES + SB - 1) / SB)    // 98

__global__ __launch_bounds__(SB) void scan1_kernel(
    const int* __restrict__ counts, int* __restrict__ incl, int* __restrict__ partials)
{
    __shared__ int s[SB];
    const int tid = threadIdx.x;
    const int i   = blockIdx.x * SB + tid;
    const int v   = (i < N_NODES) ? counts[i] : 0;
    s[tid] = v;
    __syncthreads();
    for (int off = 1; off < SB; off <<= 1) {
        const int a = (tid >= off) ? s[tid - off] : 0;
        const int t = s[tid];
        __syncthreads();
        s[tid] = t + a;
        __syncthreads();
    }
    if (i < N_NODES) incl[i] = s[tid];
    if (tid == SB - 1) partials[blockIdx.x] = s[SB - 1];
}

__global__ __launch_bounds__(128) void scan2_kernel(int* __restrict__ partials)
{
    __shared__ int s[128];
    const int t = threadIdx.x;
    const int v = (t < NB) ? partials[t] : 0;
    s[t] = v;
    __syncthreads();
    for (int off = 1; off < 128; off <<= 1) {
        const int a  = (t >= off) ? s[t - off] : 0;
        const int x0 = s[t];
        __syncthreads();
        s[t] = x0 + a;
        __syncthreads();
    }
    if (t < NB) partials[t] = s[t] - v;      // exclusive
    if (t == 127) partials[NB] = s[127];     // grand total
}

__global__ __launch_bounds__(SB) void scan3_kernel(
    const int* __restrict__ counts, const int* __restrict__ incl,
    const int* __restrict__ partials, int* __restrict__ offsets,
    int* __restrict__ cursor)
{
    const int i = blockIdx.x * SB + threadIdx.x;
    if (i < N_NODES) {
        const int off = incl[i] - counts[i] + partials[blockIdx.x];
        offsets[i] = off;
        cursor[i]  = off;                    // seed fill cursor
    }
    if (i == 0) offsets[N_NODES] = partials[NB];
}

// ---------------- fill: permute edges into row-grouped packed (col,val) ----------------
__global__ __launch_bounds__(256) void fill_kernel(
    const int* __restrict__ erow, const int* __restrict__ ecol,
    const float* __restrict__ eval, int* __restrict__ cursor,
    int2* __restrict__ edges)
{
    const int e = blockIdx.x * blockDim.x + threadIdx.x;
    if (e >= N_EDGES) return;
    const int r   = erow[e];
    const int dst = atomicAdd(&cursor[r], 1);
    edges[dst] = make_int2(ecol[e], __float_as_int(eval[e]));
}

// ---------------- SpMM: out[r] = bias + sum_e val * support_bf16[col] ----------------
__global__ __launch_bounds__(128) void spmm_kernel(
    const int* __restrict__ offsets, const int2* __restrict__ edges,
    const unsigned short* __restrict__ support,
    const float* __restrict__ bias, float* __restrict__ out)
{
    const int r   = blockIdx.x;
    const int tid = threadIdx.x;
    const int beg = offsets[r];
    const int end = offsets[r + 1];

    __shared__ int2 es[128];
    float acc = 0.f;

    for (int base = beg; base < end; base += 128) {
        const int n = min(end - base, 128);
        __syncthreads();
        if (tid < n) es[tid] = edges[base + tid];
        __syncthreads();
        for (int i = 0; i < n; ++i) {
            const int   c = es[i].x;
            const float v = __int_as_float(es[i].y);
            const unsigned short u = support[(size_t)c * OUT_F + tid];
            acc += v * __uint_as_float(((unsigned int)u) << 16);
        }
    }
    out[(size_t)r * OUT_F + tid] = acc + bias[tid];
}

extern "C" void kernel_launch(void* const* d_in, const int* in_sizes, int n_in,
                              void* d_out, int out_size, void* d_ws, size_t ws_size,
                              hipStream_t stream) {
    const float* x    = (const float*)d_in[0];
    const int*   erow = (const int*)  d_in[1];
    const int*   ecol = (const int*)  d_in[2];
    const float* eval = (const float*)d_in[3];
    const float* W    = (const float*)d_in[4];
    const float* bias = (const float*)d_in[5];
    float*       out  = (float*)d_out;

    // workspace layout (16B aligned chunks)
    char* ws = (char*)d_ws;
    unsigned short* support = (unsigned short*)ws; ws += (size_t)N_NODES * OUT_F * 2;      // 25.6 MB
    int*   counts  = (int*)ws;                     ws += (size_t)(N_NODES + 4) * 4;
    int*   offsets = (int*)ws;                     ws += (size_t)(N_NODES + 4) * 4;
    int*   cursor  = (int*)ws;                     ws += (size_t)(N_NODES + 4) * 4;
    int*   incl    = (int*)ws;                     ws += (size_t)(N_NODES + 4) * 4;
    int*   partials= (int*)ws;                     ws += (size_t)(NB + 4) * 4;
    int2*  edges   = (int2*)ws;                    ws += (size_t)N_EDGES * 8;              // 12.8 MB

    hipMemsetAsync(counts, 0, (size_t)N_NODES * 4, stream);

    // 1) support = bf16(x @ W)
    gemm_kernel<<<N_NODES / GEMM_ROWS, 128, 0, stream>>>(x, W, support);

    // 2) histogram of destination rows
    hist_kernel<<<(N_EDGES + 255) / 256, 256, 0, stream>>>(erow, counts);

    // 3) coalesced 3-phase exclusive scan (also seeds cursor)
    scan1_kernel<<<NB, SB, 0, stream>>>(counts, incl, partials);
    scan2_kernel<<<1, 128, 0, stream>>>(partials);
    scan3_kernel<<<NB, SB, 0, stream>>>(counts, incl, partials, offsets, cursor);

    // 4) permute edges into row-grouped packed (col, val)
    fill_kernel<<<(N_EDGES + 255) / 256, 256, 0, stream>>>(
        erow, ecol, eval, cursor, edges);

    // 5) segment-reduce SpMM from bf16 support, bias fused
    spmm_kernel<<<N_NODES, 128, 0, stream>>>(
        offsets, edges, support, bias, out);
}

// Round 4
// 287.653 us; speedup vs baseline: 9.8186x; 1.4159x over previous
//
#include <hip/hip_runtime.h>
#include <hip/hip_bf16.h>

#define N_NODES 100000
#define N_EDGES 1600000
#define IN_F 256
#define OUT_F 128

typedef __attribute__((ext_vector_type(8))) short bhalf8;
typedef __attribute__((ext_vector_type(4))) float f32x4;

static __device__ __forceinline__ unsigned short f2bfs(float f) {
    __hip_bfloat16 h = __float2bfloat16(f);   // RNE; compiler emits v_cvt_pk when pairable
    return *reinterpret_cast<unsigned short*>(&h);
}
static __device__ __forceinline__ float bf2f(unsigned int u16) {
    return __uint_as_float(u16 << 16);
}

// ---------------- W^T pre-pass: Wt[col][k] = bf16(W[k][col]) ----------------
__global__ __launch_bounds__(256) void wt_kernel(
    const float* __restrict__ W, unsigned short* __restrict__ Wt)
{
    const int idx = blockIdx.x * 256 + threadIdx.x;   // 32768 total
    const int col = idx >> 8;
    const int k   = idx & 255;
    Wt[idx] = f2bfs(W[(size_t)k * OUT_F + col]);
}

// ---------------- MFMA GEMM: support(bf16) = x @ W ----------------
// Block: 256 threads = 4 waves, 128 rows. Full W^T (128x256 bf16) in LDS,
// XOR-swizzled. A-fragments loaded global->reg from fp32 x, cvt to bf16.
__global__ __launch_bounds__(256) void gemm_mfma_kernel(
    const float* __restrict__ x, const unsigned short* __restrict__ Wt,
    unsigned short* __restrict__ support)
{
    __shared__ unsigned short Bs[128 * 256];   // 64 KB, row stride 512 B

    const int tid = threadIdx.x;

    // Stage W^T: 2 threads per col-row, 256 B each, swizzled uint4 slots.
    {
        const int row  = tid >> 1;       // col of W (0..127)
        const int half = tid & 1;        // which 128-short half of the k-range
        const uint4* src = (const uint4*)(Wt + (size_t)row * 256 + half * 128);
        uint4* dstbase   = (uint4*)(Bs + (size_t)row * 256 + half * 128);
        const int sw = row & 7;
        #pragma unroll
        for (int i = 0; i < 16; ++i)
            dstbase[i ^ sw] = src[i];    // byte ^= ((row&7)<<4)
    }
    __syncthreads();

    const int wave = tid >> 6, lane = tid & 63;
    const int r_lo = lane & 15;          // A row within frag / B col within frag
    const int kq   = lane >> 4;          // k-quarter
    const int row0 = blockIdx.x * 128 + wave * 32;

    const float* xa0 = x + (size_t)min(row0 + r_lo,      N_NODES - 1) * IN_F + kq * 8;
    const float* xa1 = x + (size_t)min(row0 + 16 + r_lo, N_NODES - 1) * IN_F + kq * 8;

    f32x4 acc[2][8];
    #pragma unroll
    for (int f = 0; f < 2; ++f)
        #pragma unroll
        for (int c = 0; c < 8; ++c) acc[f][c] = (f32x4)0.f;

    #pragma unroll
    for (int ks = 0; ks < 8; ++ks) {                 // k0 = ks*32
        const float4 a0l = *(const float4*)(xa0 + ks * 32);
        const float4 a0h = *(const float4*)(xa0 + ks * 32 + 4);
        const float4 a1l = *(const float4*)(xa1 + ks * 32);
        const float4 a1h = *(const float4*)(xa1 + ks * 32 + 4);

        bhalf8 A0, A1;
        A0[0] = (short)f2bfs(a0l.x); A0[1] = (short)f2bfs(a0l.y);
        A0[2] = (short)f2bfs(a0l.z); A0[3] = (short)f2bfs(a0l.w);
        A0[4] = (short)f2bfs(a0h.x); A0[5] = (short)f2bfs(a0h.y);
        A0[6] = (short)f2bfs(a0h.z); A0[7] = (short)f2bfs(a0h.w);
        A1[0] = (short)f2bfs(a1l.x); A1[1] = (short)f2bfs(a1l.y);
        A1[2] = (short)f2bfs(a1l.z); A1[3] = (short)f2bfs(a1l.w);
        A1[4] = (short)f2bfs(a1h.x); A1[5] = (short)f2bfs(a1h.y);
        A1[6] = (short)f2bfs(a1h.z); A1[7] = (short)f2bfs(a1h.w);

        #pragma unroll
        for (int cf = 0; cf < 8; ++cf) {
            const int col = cf * 16 + r_lo;
            // shorts offset within row, swizzled: (ks*32 + kq*8) ^ ((col&7)<<3)
            const int off = ((ks * 32 + kq * 8) ^ ((col & 7) << 3));
            const bhalf8 B = *(const bhalf8*)(Bs + (size_t)col * 256 + off);
            acc[0][cf] = __builtin_amdgcn_mfma_f32_16x16x32_bf16(A0, B, acc[0][cf], 0, 0, 0);
            acc[1][cf] = __builtin_amdgcn_mfma_f32_16x16x32_bf16(A1, B, acc[1][cf], 0, 0, 0);
        }
    }

    // D[(lane>>4)*4 + r][lane&15] per 16x16 frag
    #pragma unroll
    for (int f = 0; f < 2; ++f)
        #pragma unroll
        for (int r = 0; r < 4; ++r) {
            const int row = row0 + f * 16 + kq * 4 + r;
            if (row < N_NODES) {
                unsigned short* dst = support + (size_t)row * OUT_F + r_lo;
                #pragma unroll
                for (int cf = 0; cf < 8; ++cf)
                    dst[cf * 16] = f2bfs(acc[f][cf][r]);
            }
        }
}

// ---------------- CSR build ----------------
__global__ __launch_bounds__(256) void hist_kernel(
    const int* __restrict__ erow, int* __restrict__ counts)
{
    const int e = blockIdx.x * blockDim.x + threadIdx.x;
    if (e < N_EDGES) atomicAdd(&counts[erow[e]], 1);
}

#define SB 1024
#define NB ((N_NODES + SB - 1) / SB)    // 98

__global__ __launch_bounds__(SB) void scan1_kernel(
    const int* __restrict__ counts, int* __restrict__ incl, int* __restrict__ partials)
{
    __shared__ int s[SB];
    const int tid = threadIdx.x;
    const int i   = blockIdx.x * SB + tid;
    const int v   = (i < N_NODES) ? counts[i] : 0;
    s[tid] = v;
    __syncthreads();
    for (int off = 1; off < SB; off <<= 1) {
        const int a = (tid >= off) ? s[tid - off] : 0;
        const int t = s[tid];
        __syncthreads();
        s[tid] = t + a;
        __syncthreads();
    }
    if (i < N_NODES) incl[i] = s[tid];
    if (tid == SB - 1) partials[blockIdx.x] = s[SB - 1];
}

__global__ __launch_bounds__(128) void scan2_kernel(int* __restrict__ partials)
{
    __shared__ int s[128];
    const int t = threadIdx.x;
    const int v = (t < NB) ? partials[t] : 0;
    s[t] = v;
    __syncthreads();
    for (int off = 1; off < 128; off <<= 1) {
        const int a  = (t >= off) ? s[t - off] : 0;
        const int x0 = s[t];
        __syncthreads();
        s[t] = x0 + a;
        __syncthreads();
    }
    if (t < NB) partials[t] = s[t] - v;      // exclusive
    if (t == 127) partials[NB] = s[127];     // grand total
}

__global__ __launch_bounds__(SB) void scan3_kernel(
    const int* __restrict__ counts, const int* __restrict__ incl,
    const int* __restrict__ partials, int* __restrict__ offsets,
    int* __restrict__ cursor)
{
    const int i = blockIdx.x * SB + threadIdx.x;
    if (i < N_NODES) {
        const int off = incl[i] - counts[i] + partials[blockIdx.x];
        offsets[i] = off;
        cursor[i]  = off;
    }
    if (i == 0) offsets[N_NODES] = partials[NB];
}

__global__ __launch_bounds__(256) void fill_kernel(
    const int* __restrict__ erow, const int* __restrict__ ecol,
    const float* __restrict__ eval, int* __restrict__ cursor,
    int2* __restrict__ edges)
{
    const int e = blockIdx.x * blockDim.x + threadIdx.x;
    if (e >= N_EDGES) return;
    const int r   = erow[e];
    const int dst = atomicAdd(&cursor[r], 1);
    edges[dst] = make_int2(ecol[e], __float_as_int(eval[e]));
}

// ---------------- SpMM: 1 wave per row, 2 features/lane ----------------
__global__ __launch_bounds__(64) void spmm_kernel(
    const int* __restrict__ offsets, const int2* __restrict__ edges,
    const unsigned short* __restrict__ support,
    const float* __restrict__ bias, float* __restrict__ out)
{
    const int r    = blockIdx.x;
    const int lane = threadIdx.x;
    const int beg  = offsets[r];
    const int end  = offsets[r + 1];

    __shared__ int2 es[64];
    float ax = 0.f, ay = 0.f;

    for (int base = beg; base < end; base += 64) {
        const int n = min(end - base, 64);
        __syncthreads();
        if (lane < n) es[lane] = edges[base + lane];
        __syncthreads();
        for (int i = 0; i < n; ++i) {
            const int   c = es[i].x;
            const float v = __int_as_float(es[i].y);
            const unsigned int u = *(const unsigned int*)(support + (size_t)c * OUT_F + lane * 2);
            ax += v * bf2f(u & 0xFFFFu);
            ay += v * __uint_as_float(u & 0xFFFF0000u);
        }
    }
    const float2 b = ((const float2*)bias)[lane];
    ((float2*)(out + (size_t)r * OUT_F))[lane] = make_float2(ax + b.x, ay + b.y);
}

extern "C" void kernel_launch(void* const* d_in, const int* in_sizes, int n_in,
                              void* d_out, int out_size, void* d_ws, size_t ws_size,
                              hipStream_t stream) {
    const float* x    = (const float*)d_in[0];
    const int*   erow = (const int*)  d_in[1];
    const int*   ecol = (const int*)  d_in[2];
    const float* eval = (const float*)d_in[3];
    const float* W    = (const float*)d_in[4];
    const float* bias = (const float*)d_in[5];
    float*       out  = (float*)d_out;

    // workspace layout (16B-aligned chunks)
    char* ws = (char*)d_ws;
    unsigned short* support = (unsigned short*)ws; ws += (size_t)N_NODES * OUT_F * 2;  // 25.6 MB
    unsigned short* Wt      = (unsigned short*)ws; ws += (size_t)OUT_F * IN_F * 2;     // 64 KB
    int*   counts  = (int*)ws;                     ws += (size_t)(N_NODES + 4) * 4;
    int*   offsets = (int*)ws;                     ws += (size_t)(N_NODES + 4) * 4;
    int*   cursor  = (int*)ws;                     ws += (size_t)(N_NODES + 4) * 4;
    int*   incl    = (int*)ws;                     ws += (size_t)(N_NODES + 4) * 4;
    int*   partials= (int*)ws;                     ws += (size_t)(NB + 6) * 4;
    int2*  edges   = (int2*)ws;                    ws += (size_t)N_EDGES * 8;          // 12.8 MB

    hipMemsetAsync(counts, 0, (size_t)N_NODES * 4, stream);

    // W^T bf16 pre-pass, then MFMA GEMM
    wt_kernel<<<(OUT_F * IN_F) / 256, 256, 0, stream>>>(W, Wt);
    gemm_mfma_kernel<<<(N_NODES + 127) / 128, 256, 0, stream>>>(x, Wt, support);

    // CSR build
    hist_kernel<<<(N_EDGES + 255) / 256, 256, 0, stream>>>(erow, counts);
    scan1_kernel<<<NB, SB, 0, stream>>>(counts, incl, partials);
    scan2_kernel<<<1, 128, 0, stream>>>(partials);
    scan3_kernel<<<NB, SB, 0, stream>>>(counts, incl, partials, offsets, cursor);
    fill_kernel<<<(N_EDGES + 255) / 256, 256, 0, stream>>>(
        erow, ecol, eval, cursor, edges);

    // segment-reduce SpMM, bias fused
    spmm_kernel<<<N_NODES, 64, 0, stream>>>(offsets, edges, support, bias, out);
}

// Round 5
// 204.837 us; speedup vs baseline: 13.7883x; 1.4043x over previous
//
#include <hip/hip_runtime.h>
#include <hip/hip_bf16.h>

#define N_NODES 100000
#define N_EDGES 1600000
#define IN_F 256
#define OUT_F 128

#define NBUCK 782          // ceil(100000 / 128) rows-per-bucket = 128
#define CH 4096            // edges per bscatter block
#define NCHB ((N_EDGES + CH - 1) / CH)   // 391
#define MAXB 3072          // LDS edge capacity per bucket chunk in bspmm

typedef __attribute__((ext_vector_type(8))) short bhalf8;
typedef __attribute__((ext_vector_type(4))) float f32x4;

static __device__ __forceinline__ unsigned short f2bfs(float f) {
    __hip_bfloat16 h = __float2bfloat16(f);
    return *reinterpret_cast<unsigned short*>(&h);
}
static __device__ __forceinline__ float bf2f(unsigned int u16) {
    return __uint_as_float(u16 << 16);
}

// ---------------- W^T pre-pass: Wt[col][k] = bf16(W[k][col]) ----------------
__global__ __launch_bounds__(256) void wt_kernel(
    const float* __restrict__ W, unsigned short* __restrict__ Wt)
{
    const int idx = blockIdx.x * 256 + threadIdx.x;
    const int col = idx >> 8;
    const int k   = idx & 255;
    Wt[idx] = f2bfs(W[(size_t)k * OUT_F + col]);
}

// ---------------- MFMA GEMM: support(bf16) = x @ W ----------------
__global__ __launch_bounds__(256) void gemm_mfma_kernel(
    const float* __restrict__ x, const unsigned short* __restrict__ Wt,
    unsigned short* __restrict__ support)
{
    __shared__ unsigned short Bs[128 * 256];   // 64 KB

    const int tid = threadIdx.x;
    {
        const int row  = tid >> 1;
        const int half = tid & 1;
        const uint4* src = (const uint4*)(Wt + (size_t)row * 256 + half * 128);
        uint4* dstbase   = (uint4*)(Bs + (size_t)row * 256 + half * 128);
        const int sw = row & 7;
        #pragma unroll
        for (int i = 0; i < 16; ++i)
            dstbase[i ^ sw] = src[i];
    }
    __syncthreads();

    const int wave = tid >> 6, lane = tid & 63;
    const int r_lo = lane & 15;
    const int kq   = lane >> 4;
    const int row0 = blockIdx.x * 128 + wave * 32;

    const float* xa0 = x + (size_t)min(row0 + r_lo,      N_NODES - 1) * IN_F + kq * 8;
    const float* xa1 = x + (size_t)min(row0 + 16 + r_lo, N_NODES - 1) * IN_F + kq * 8;

    f32x4 acc[2][8];
    #pragma unroll
    for (int f = 0; f < 2; ++f)
        #pragma unroll
        for (int c = 0; c < 8; ++c) acc[f][c] = (f32x4)0.f;

    #pragma unroll
    for (int ks = 0; ks < 8; ++ks) {
        const float4 a0l = *(const float4*)(xa0 + ks * 32);
        const float4 a0h = *(const float4*)(xa0 + ks * 32 + 4);
        const float4 a1l = *(const float4*)(xa1 + ks * 32);
        const float4 a1h = *(const float4*)(xa1 + ks * 32 + 4);

        bhalf8 A0, A1;
        A0[0] = (short)f2bfs(a0l.x); A0[1] = (short)f2bfs(a0l.y);
        A0[2] = (short)f2bfs(a0l.z); A0[3] = (short)f2bfs(a0l.w);
        A0[4] = (short)f2bfs(a0h.x); A0[5] = (short)f2bfs(a0h.y);
        A0[6] = (short)f2bfs(a0h.z); A0[7] = (short)f2bfs(a0h.w);
        A1[0] = (short)f2bfs(a1l.x); A1[1] = (short)f2bfs(a1l.y);
        A1[2] = (short)f2bfs(a1l.z); A1[3] = (short)f2bfs(a1l.w);
        A1[4] = (short)f2bfs(a1h.x); A1[5] = (short)f2bfs(a1h.y);
        A1[6] = (short)f2bfs(a1h.z); A1[7] = (short)f2bfs(a1h.w);

        #pragma unroll
        for (int cf = 0; cf < 8; ++cf) {
            const int col = cf * 16 + r_lo;
            const int off = ((ks * 32 + kq * 8) ^ ((col & 7) << 3));
            const bhalf8 B = *(const bhalf8*)(Bs + (size_t)col * 256 + off);
            acc[0][cf] = __builtin_amdgcn_mfma_f32_16x16x32_bf16(A0, B, acc[0][cf], 0, 0, 0);
            acc[1][cf] = __builtin_amdgcn_mfma_f32_16x16x32_bf16(A1, B, acc[1][cf], 0, 0, 0);
        }
    }

    #pragma unroll
    for (int f = 0; f < 2; ++f)
        #pragma unroll
        for (int r = 0; r < 4; ++r) {
            const int row = row0 + f * 16 + kq * 4 + r;
            if (row < N_NODES) {
                unsigned short* dst = support + (size_t)row * OUT_F + r_lo;
                #pragma unroll
                for (int cf = 0; cf < 8; ++cf)
                    dst[cf * 16] = f2bfs(acc[f][cf][r]);
            }
        }
}

// ---------------- bucket histogram (bucket = row >> 7) ----------------
__global__ __launch_bounds__(256) void bhist_kernel(
    const int* __restrict__ erow, int* __restrict__ bcnt)
{
    __shared__ int h[NBUCK];
    const int tid = threadIdx.x;
    for (int i = tid; i < NBUCK; i += 256) h[i] = 0;
    __syncthreads();
    const int e0 = blockIdx.x * CH;
    const int e1 = min(e0 + CH, N_EDGES);
    for (int e = e0 + tid; e < e1; e += 256)
        atomicAdd(&h[erow[e] >> 7], 1);
    __syncthreads();
    for (int i = tid; i < NBUCK; i += 256)
        if (h[i]) atomicAdd(&bcnt[i], h[i]);
}

// ---------------- bucket scan: boffs = exclusive scan, seed bcur ----------------
__global__ __launch_bounds__(1024) void bscan_kernel(
    const int* __restrict__ bcnt, int* __restrict__ boffs, int* __restrict__ bcur)
{
    __shared__ int s[1024];
    const int t = threadIdx.x;
    const int v = (t < NBUCK) ? bcnt[t] : 0;
    s[t] = v;
    __syncthreads();
    for (int off = 1; off < 1024; off <<= 1) {
        const int a  = (t >= off) ? s[t - off] : 0;
        const int x0 = s[t];
        __syncthreads();
        s[t] = x0 + a;
        __syncthreads();
    }
    if (t < NBUCK) {
        const int excl = s[t] - v;
        boffs[t] = excl;
        bcur[t]  = excl;
    }
    if (t == 1023) boffs[NBUCK] = s[1023];
}

// ---------------- bucket scatter: group edges by bucket, run-writes ----------------
__global__ __launch_bounds__(256) void bscatter_kernel(
    const int* __restrict__ erow, const int* __restrict__ ecol,
    const float* __restrict__ eval, int* __restrict__ bcur,
    int2* __restrict__ ebuf)
{
    __shared__ int h[NBUCK];                 // per-block bucket counts
    __shared__ int cur[NBUCK];               // local cursors (end = base+cnt)
    __shared__ int gbase[NBUCK];             // global run bases
    __shared__ int ps[256];
    __shared__ unsigned short bb[CH];        // bucket id per LDS slot
    __shared__ int2 buf[CH];                 // bucket-grouped edges

    const int tid = threadIdx.x;
    const int e0  = blockIdx.x * CH;
    const int e1  = min(e0 + CH, N_EDGES);
    const int n   = e1 - e0;

    for (int i = tid; i < NBUCK; i += 256) h[i] = 0;
    __syncthreads();

    // phase A: histogram
    for (int e = e0 + tid; e < e1; e += 256)
        atomicAdd(&h[erow[e] >> 7], 1);
    __syncthreads();

    // scan h -> exclusive local bases in cur (h preserved)
    {
        const int idx0 = tid * 4;
        int sum = 0;
        #pragma unroll
        for (int k = 0; k < 4; ++k) { const int ii = idx0 + k; if (ii < NBUCK) sum += h[ii]; }
        ps[tid] = sum;
        __syncthreads();
        for (int off = 1; off < 256; off <<= 1) {
            const int a  = (tid >= off) ? ps[tid - off] : 0;
            const int x0 = ps[tid];
            __syncthreads();
            ps[tid] = x0 + a;
            __syncthreads();
        }
        int run = (tid == 0) ? 0 : ps[tid - 1];
        #pragma unroll
        for (int k = 0; k < 4; ++k) {
            const int ii = idx0 + k;
            if (ii < NBUCK) { cur[ii] = run; run += h[ii]; }
        }
    }
    __syncthreads();

    // phase B: place into LDS, bucket-grouped
    for (int e = e0 + tid; e < e1; e += 256) {
        const int r = erow[e];
        const int b = r >> 7;
        const int p = atomicAdd(&cur[b], 1);
        buf[p] = make_int2(((r & 127) << 17) | ecol[e], __float_as_int(eval[e]));
        bb[p]  = (unsigned short)b;
    }
    __syncthreads();

    // allocate global runs
    for (int i = tid; i < NBUCK; i += 256)
        gbase[i] = h[i] ? atomicAdd(&bcur[i], h[i]) : 0;
    __syncthreads();

    // coalesced copy out (slot-parallel)
    for (int i = tid; i < n; i += 256) {
        const int b  = bb[i];
        const int lb = cur[b] - h[b];            // local base
        ebuf[gbase[b] + (i - lb)] = buf[i];
    }
}

// ---------------- bucket SpMM: group by local row in LDS, reduce, +bias ----------------
__global__ __launch_bounds__(256) void bspmm_kernel(
    const int* __restrict__ boffs, const int2* __restrict__ ebuf,
    const unsigned short* __restrict__ support,
    const float* __restrict__ bias, float* __restrict__ out)
{
    __shared__ int2 srt[MAXB];
    __shared__ int rc[128];     // per-row counts
    __shared__ int rb[129];     // per-row segment bounds
    __shared__ int cc[128];     // cursors

    const int b    = blockIdx.x;
    const int beg  = boffs[b];
    const int end  = boffs[b + 1];
    const int row0 = b << 7;
    const int nrows = min(128, N_NODES - row0);
    const int tid  = threadIdx.x;
    const int wave = tid >> 6, lane = tid & 63;
    const float2 bv = ((const float2*)bias)[lane];

    for (int cbeg = beg; cbeg == beg || cbeg < end; cbeg += MAXB) {
        const int n = min(end - cbeg, MAXB);

        if (tid < 128) rc[tid] = 0;
        __syncthreads();
        for (int i = tid; i < n; i += 256)
            atomicAdd(&rc[(unsigned)ebuf[cbeg + i].x >> 17], 1);
        __syncthreads();

        // scan 128 bins
        if (tid < 128) cc[tid] = rc[tid];
        __syncthreads();
        for (int off = 1; off < 128; off <<= 1) {
            int a = 0;
            if (tid < 128) a = (tid >= off) ? cc[tid - off] : 0;
            __syncthreads();
            if (tid < 128) cc[tid] += a;
            __syncthreads();
        }
        if (tid < 128) { rb[tid + 1] = cc[tid]; cc[tid] -= rc[tid]; }
        if (tid == 0) rb[0] = 0;
        __syncthreads();

        // place into srt grouped by local row
        for (int i = tid; i < n; i += 256) {
            const int2 e = ebuf[cbeg + i];
            const int lr = (unsigned)e.x >> 17;
            srt[atomicAdd(&cc[lr], 1)] = e;
        }
        __syncthreads();

        // reduce: wave w handles rows [w*32, w*32+32)
        const int lr_end = min(wave * 32 + 32, nrows);
        for (int lr = wave * 32; lr < lr_end; ++lr) {
            const int s  = rb[lr];
            const int t2 = rb[lr + 1];
            float ax = 0.f, ay = 0.f, ax2 = 0.f, ay2 = 0.f;
            int j = s;
            for (; j + 2 <= t2; j += 2) {
                const int2 e0 = srt[j], e1 = srt[j + 1];
                const unsigned u0 = *(const unsigned*)(support + ((size_t)(e0.x & 0x1FFFF) << 7) + lane * 2);
                const unsigned u1 = *(const unsigned*)(support + ((size_t)(e1.x & 0x1FFFF) << 7) + lane * 2);
                const float v0 = __int_as_float(e0.y), v1 = __int_as_float(e1.y);
                ax  += v0 * bf2f(u0 & 0xFFFFu);
                ay  += v0 * __uint_as_float(u0 & 0xFFFF0000u);
                ax2 += v1 * bf2f(u1 & 0xFFFFu);
                ay2 += v1 * __uint_as_float(u1 & 0xFFFF0000u);
            }
            if (j < t2) {
                const int2 e0 = srt[j];
                const unsigned u0 = *(const unsigned*)(support + ((size_t)(e0.x & 0x1FFFF) << 7) + lane * 2);
                const float v0 = __int_as_float(e0.y);
                ax += v0 * bf2f(u0 & 0xFFFFu);
                ay += v0 * __uint_as_float(u0 & 0xFFFF0000u);
            }
            ax += ax2; ay += ay2;
            float2* o = (float2*)(out + ((size_t)(row0 + lr) << 7)) + lane;
            if (cbeg == beg) *o = make_float2(ax + bv.x, ay + bv.y);
            else { const float2 p = *o; *o = make_float2(p.x + ax, p.y + ay); }
        }
        __syncthreads();
    }
}

extern "C" void kernel_launch(void* const* d_in, const int* in_sizes, int n_in,
                              void* d_out, int out_size, void* d_ws, size_t ws_size,
                              hipStream_t stream) {
    const float* x    = (const float*)d_in[0];
    const int*   erow = (const int*)  d_in[1];
    const int*   ecol = (const int*)  d_in[2];
    const float* eval = (const float*)d_in[3];
    const float* W    = (const float*)d_in[4];
    const float* bias = (const float*)d_in[5];
    float*       out  = (float*)d_out;

    // workspace layout (16B-aligned chunks)
    char* ws = (char*)d_ws;
    unsigned short* support = (unsigned short*)ws; ws += (size_t)N_NODES * OUT_F * 2;  // 25.6 MB
    unsigned short* Wt      = (unsigned short*)ws; ws += (size_t)OUT_F * IN_F * 2;     // 64 KB
    int*  bcnt  = (int*)ws;                        ws += 3136;                          // >= NBUCK*4
    int*  boffs = (int*)ws;                        ws += 3152;                          // >= (NBUCK+1)*4
    int*  bcur  = (int*)ws;                        ws += 3136;
    int2* ebuf  = (int2*)ws;                       ws += (size_t)N_EDGES * 8;           // 12.8 MB

    hipMemsetAsync(bcnt, 0, NBUCK * 4, stream);

    wt_kernel<<<(OUT_F * IN_F) / 256, 256, 0, stream>>>(W, Wt);
    gemm_mfma_kernel<<<(N_NODES + 127) / 128, 256, 0, stream>>>(x, Wt, support);

    bhist_kernel<<<NCHB, 256, 0, stream>>>(erow, bcnt);
    bscan_kernel<<<1, 1024, 0, stream>>>(bcnt, boffs, bcur);
    bscatter_kernel<<<NCHB, 256, 0, stream>>>(erow, ecol, eval, bcur, ebuf);

    bspmm_kernel<<<NBUCK, 256, 0, stream>>>(boffs, ebuf, support, bias, out);
}

// Round 6
// 181.004 us; speedup vs baseline: 15.6038x; 1.1317x over previous
//
#include <hip/hip_runtime.h>
#include <hip/hip_bf16.h>

#define N_NODES 100000
#define N_EDGES 1600000
#define IN_F 256
#define OUT_F 128

#define NBUCK 782          // ceil(100000 / 128), 128 rows per parent bucket
#define CH 4096            // edges per bscatter block
#define NCHB ((N_EDGES + CH - 1) / CH)   // 391
#define INCH 3072          // input-edge chunk per bspmm block (srt capacity)

typedef __attribute__((ext_vector_type(8))) short bhalf8;
typedef __attribute__((ext_vector_type(4))) float f32x4;

static __device__ __forceinline__ unsigned short f2bfs(float f) {
    __hip_bfloat16 h = __float2bfloat16(f);
    return *reinterpret_cast<unsigned short*>(&h);
}
static __device__ __forceinline__ float bf2f(unsigned int u16) {
    return __uint_as_float(u16 << 16);
}

// ---------------- W^T pre-pass: Wt[col][k] = bf16(W[k][col]) ----------------
__global__ __launch_bounds__(256) void wt_kernel(
    const float* __restrict__ W, unsigned short* __restrict__ Wt)
{
    const int idx = blockIdx.x * 256 + threadIdx.x;
    const int col = idx >> 8;
    const int k   = idx & 255;
    Wt[idx] = f2bfs(W[(size_t)k * OUT_F + col]);
}

// ---------------- MFMA GEMM: support(bf16) = x @ W ----------------
__global__ __launch_bounds__(256) void gemm_mfma_kernel(
    const float* __restrict__ x, const unsigned short* __restrict__ Wt,
    unsigned short* __restrict__ support)
{
    __shared__ unsigned short Bs[128 * 256];   // 64 KB

    const int tid = threadIdx.x;
    {
        const int row  = tid >> 1;
        const int half = tid & 1;
        const uint4* src = (const uint4*)(Wt + (size_t)row * 256 + half * 128);
        uint4* dstbase   = (uint4*)(Bs + (size_t)row * 256 + half * 128);
        const int sw = row & 7;
        #pragma unroll
        for (int i = 0; i < 16; ++i)
            dstbase[i ^ sw] = src[i];
    }
    __syncthreads();

    const int wave = tid >> 6, lane = tid & 63;
    const int r_lo = lane & 15;
    const int kq   = lane >> 4;
    const int row0 = blockIdx.x * 128 + wave * 32;

    const float* xa0 = x + (size_t)min(row0 + r_lo,      N_NODES - 1) * IN_F + kq * 8;
    const float* xa1 = x + (size_t)min(row0 + 16 + r_lo, N_NODES - 1) * IN_F + kq * 8;

    f32x4 acc[2][8];
    #pragma unroll
    for (int f = 0; f < 2; ++f)
        #pragma unroll
        for (int c = 0; c < 8; ++c) acc[f][c] = (f32x4)0.f;

    #pragma unroll
    for (int ks = 0; ks < 8; ++ks) {
        const float4 a0l = *(const float4*)(xa0 + ks * 32);
        const float4 a0h = *(const float4*)(xa0 + ks * 32 + 4);
        const float4 a1l = *(const float4*)(xa1 + ks * 32);
        const float4 a1h = *(const float4*)(xa1 + ks * 32 + 4);

        bhalf8 A0, A1;
        A0[0] = (short)f2bfs(a0l.x); A0[1] = (short)f2bfs(a0l.y);
        A0[2] = (short)f2bfs(a0l.z); A0[3] = (short)f2bfs(a0l.w);
        A0[4] = (short)f2bfs(a0h.x); A0[5] = (short)f2bfs(a0h.y);
        A0[6] = (short)f2bfs(a0h.z); A0[7] = (short)f2bfs(a0h.w);
        A1[0] = (short)f2bfs(a1l.x); A1[1] = (short)f2bfs(a1l.y);
        A1[2] = (short)f2bfs(a1l.z); A1[3] = (short)f2bfs(a1l.w);
        A1[4] = (short)f2bfs(a1h.x); A1[5] = (short)f2bfs(a1h.y);
        A1[6] = (short)f2bfs(a1h.z); A1[7] = (short)f2bfs(a1h.w);

        #pragma unroll
        for (int cf = 0; cf < 8; ++cf) {
            const int col = cf * 16 + r_lo;
            const int off = ((ks * 32 + kq * 8) ^ ((col & 7) << 3));
            const bhalf8 B = *(const bhalf8*)(Bs + (size_t)col * 256 + off);
            acc[0][cf] = __builtin_amdgcn_mfma_f32_16x16x32_bf16(A0, B, acc[0][cf], 0, 0, 0);
            acc[1][cf] = __builtin_amdgcn_mfma_f32_16x16x32_bf16(A1, B, acc[1][cf], 0, 0, 0);
        }
    }

    #pragma unroll
    for (int f = 0; f < 2; ++f)
        #pragma unroll
        for (int r = 0; r < 4; ++r) {
            const int row = row0 + f * 16 + kq * 4 + r;
            if (row < N_NODES) {
                unsigned short* dst = support + (size_t)row * OUT_F + r_lo;
                #pragma unroll
                for (int cf = 0; cf < 8; ++cf)
                    dst[cf * 16] = f2bfs(acc[f][cf][r]);
            }
        }
}

// ---------------- bucket histogram (bucket = row >> 7) ----------------
__global__ __launch_bounds__(256) void bhist_kernel(
    const int* __restrict__ erow, int* __restrict__ bcnt)
{
    __shared__ int h[NBUCK];
    const int tid = threadIdx.x;
    for (int i = tid; i < NBUCK; i += 256) h[i] = 0;
    __syncthreads();
    const int e0 = blockIdx.x * CH;
    const int e1 = min(e0 + CH, N_EDGES);
    for (int e = e0 + tid; e < e1; e += 256)
        atomicAdd(&h[erow[e] >> 7], 1);
    __syncthreads();
    for (int i = tid; i < NBUCK; i += 256)
        if (h[i]) atomicAdd(&bcnt[i], h[i]);
}

// ---------------- bucket scan: boffs = exclusive scan, seed bcur ----------------
__global__ __launch_bounds__(1024) void bscan_kernel(
    const int* __restrict__ bcnt, int* __restrict__ boffs, int* __restrict__ bcur)
{
    __shared__ int s[1024];
    const int t = threadIdx.x;
    const int v = (t < NBUCK) ? bcnt[t] : 0;
    s[t] = v;
    __syncthreads();
    for (int off = 1; off < 1024; off <<= 1) {
        const int a  = (t >= off) ? s[t - off] : 0;
        const int x0 = s[t];
        __syncthreads();
        s[t] = x0 + a;
        __syncthreads();
    }
    if (t < NBUCK) {
        const int excl = s[t] - v;
        boffs[t] = excl;
        bcur[t]  = excl;
    }
    if (t == 1023) boffs[NBUCK] = s[1023];
}

// ---------------- bucket scatter: group edges by bucket, run-writes ----------------
__global__ __launch_bounds__(256) void bscatter_kernel(
    const int* __restrict__ erow, const int* __restrict__ ecol,
    const float* __restrict__ eval, int* __restrict__ bcur,
    int2* __restrict__ ebuf)
{
    __shared__ int h[NBUCK];
    __shared__ int cur[NBUCK];
    __shared__ int gbase[NBUCK];
    __shared__ int ps[256];
    __shared__ unsigned short bb[CH];
    __shared__ int2 buf[CH];

    const int tid = threadIdx.x;
    const int e0  = blockIdx.x * CH;
    const int e1  = min(e0 + CH, N_EDGES);
    const int n   = e1 - e0;

    for (int i = tid; i < NBUCK; i += 256) h[i] = 0;
    __syncthreads();

    for (int e = e0 + tid; e < e1; e += 256)
        atomicAdd(&h[erow[e] >> 7], 1);
    __syncthreads();

    {
        const int idx0 = tid * 4;
        int sum = 0;
        #pragma unroll
        for (int k = 0; k < 4; ++k) { const int ii = idx0 + k; if (ii < NBUCK) sum += h[ii]; }
        ps[tid] = sum;
        __syncthreads();
        for (int off = 1; off < 256; off <<= 1) {
            const int a  = (tid >= off) ? ps[tid - off] : 0;
            const int x0 = ps[tid];
            __syncthreads();
            ps[tid] = x0 + a;
            __syncthreads();
        }
        int run = (tid == 0) ? 0 : ps[tid - 1];
        #pragma unroll
        for (int k = 0; k < 4; ++k) {
            const int ii = idx0 + k;
            if (ii < NBUCK) { cur[ii] = run; run += h[ii]; }
        }
    }
    __syncthreads();

    for (int e = e0 + tid; e < e1; e += 256) {
        const int r = erow[e];
        const int b = r >> 7;
        const int p = atomicAdd(&cur[b], 1);
        buf[p] = make_int2(((r & 127) << 17) | ecol[e], __float_as_int(eval[e]));
        bb[p]  = (unsigned short)b;
    }
    __syncthreads();

    for (int i = tid; i < NBUCK; i += 256)
        gbase[i] = h[i] ? atomicAdd(&bcur[i], h[i]) : 0;
    __syncthreads();

    for (int i = tid; i < n; i += 256) {
        const int b  = bb[i];
        const int lb = cur[b] - h[b];
        ebuf[gbase[b] + (i - lb)] = buf[i];
    }
}

// ---------------- bucket SpMM: half-bucket per block, 2 edges/wave ----------------
__global__ __launch_bounds__(256) void bspmm_kernel(
    const int* __restrict__ boffs, const int2* __restrict__ ebuf,
    const unsigned short* __restrict__ support,
    const float* __restrict__ bias, float* __restrict__ out)
{
    __shared__ int2 srt[INCH];
    __shared__ int rc[64];
    __shared__ int rb[65];
    __shared__ int cc[64];

    const int blk  = blockIdx.x;
    const int pb   = blk >> 1;           // parent 128-row bucket
    const int hf   = blk & 1;            // which 64-row half
    const int beg  = boffs[pb];
    const int end  = boffs[pb + 1];
    const int row0 = (pb << 7) + (hf << 6);
    if (row0 >= N_NODES) return;         // uniform across block
    const int nrows = min(64, N_NODES - row0);

    const int tid   = threadIdx.x;
    const int wave  = tid >> 6, lane = tid & 63;
    const int lhalf = lane >> 5;         // which edge of the pair
    const int l5    = lane & 31;
    const float4 bv = ((const float4*)bias)[l5];

    bool first = true;
    for (int cbeg = beg; first || cbeg < end; cbeg += INCH) {
        const int nin = min(end - cbeg, INCH);

        if (tid < 64) rc[tid] = 0;
        __syncthreads();
        for (int i = tid; i < nin; i += 256) {
            const int lr = (unsigned)ebuf[cbeg + i].x >> 17;
            if ((lr >> 6) == hf) atomicAdd(&rc[lr & 63], 1);
        }
        __syncthreads();

        if (tid < 64) cc[tid] = rc[tid];
        __syncthreads();
        for (int off = 1; off < 64; off <<= 1) {
            int a = 0;
            if (tid < 64) a = (tid >= off) ? cc[tid - off] : 0;
            __syncthreads();
            if (tid < 64) cc[tid] += a;
            __syncthreads();
        }
        if (tid < 64) { rb[tid + 1] = cc[tid]; cc[tid] -= rc[tid]; }
        if (tid == 0) rb[0] = 0;
        __syncthreads();

        for (int i = tid; i < nin; i += 256) {
            const int2 e = ebuf[cbeg + i];
            const int lr = (unsigned)e.x >> 17;
            if ((lr >> 6) == hf) srt[atomicAdd(&cc[lr & 63], 1)] = e;
        }
        __syncthreads();

        // reduce: wave w handles rows [w*16, w*16+16); 2 edges per iteration
        const int lrE = min(wave * 16 + 16, nrows);
        for (int lr = wave * 16; lr < lrE; ++lr) {
            const int s  = rb[lr];
            const int t2 = rb[lr + 1];
            float a0 = 0.f, a1 = 0.f, a2 = 0.f, a3 = 0.f;
            int j = s;
            #pragma unroll 2
            for (; j + 2 <= t2; j += 2) {
                const int2  e = srt[j + lhalf];
                const float v = __int_as_float(e.y);
                const uint2 u = *(const uint2*)(support +
                                   ((size_t)(e.x & 0x1FFFF) << 7) + l5 * 4);
                a0 += v * __uint_as_float(u.x << 16);
                a1 += v * __uint_as_float(u.x & 0xFFFF0000u);
                a2 += v * __uint_as_float(u.y << 16);
                a3 += v * __uint_as_float(u.y & 0xFFFF0000u);
            }
            if (j < t2) {
                const int2  e = srt[j];
                const float v = lhalf ? 0.f : __int_as_float(e.y);
                const uint2 u = *(const uint2*)(support +
                                   ((size_t)(e.x & 0x1FFFF) << 7) + l5 * 4);
                a0 += v * __uint_as_float(u.x << 16);
                a1 += v * __uint_as_float(u.x & 0xFFFF0000u);
                a2 += v * __uint_as_float(u.y << 16);
                a3 += v * __uint_as_float(u.y & 0xFFFF0000u);
            }
            a0 += __shfl_xor(a0, 32);
            a1 += __shfl_xor(a1, 32);
            a2 += __shfl_xor(a2, 32);
            a3 += __shfl_xor(a3, 32);
            if (lane < 32) {
                float4* o = (float4*)(out + ((size_t)(row0 + lr) << 7)) + l5;
                if (first) *o = make_float4(a0 + bv.x, a1 + bv.y, a2 + bv.z, a3 + bv.w);
                else { const float4 p = *o; *o = make_float4(p.x + a0, p.y + a1, p.z + a2, p.w + a3); }
            }
        }
        first = false;
        __syncthreads();
    }
}

extern "C" void kernel_launch(void* const* d_in, const int* in_sizes, int n_in,
                              void* d_out, int out_size, void* d_ws, size_t ws_size,
                              hipStream_t stream) {
    const float* x    = (const float*)d_in[0];
    const int*   erow = (const int*)  d_in[1];
    const int*   ecol = (const int*)  d_in[2];
    const float* eval = (const float*)d_in[3];
    const float* W    = (const float*)d_in[4];
    const float* bias = (const float*)d_in[5];
    float*       out  = (float*)d_out;

    // workspace layout (16B-aligned chunks)
    char* ws = (char*)d_ws;
    unsigned short* support = (unsigned short*)ws; ws += (size_t)N_NODES * OUT_F * 2;  // 25.6 MB
    unsigned short* Wt      = (unsigned short*)ws; ws += (size_t)OUT_F * IN_F * 2;     // 64 KB
    int*  bcnt  = (int*)ws;                        ws += 3136;
    int*  boffs = (int*)ws;                        ws += 3152;
    int*  bcur  = (int*)ws;                        ws += 3136;
    int2* ebuf  = (int2*)ws;                       ws += (size_t)N_EDGES * 8;           // 12.8 MB

    hipMemsetAsync(bcnt, 0, NBUCK * 4, stream);

    wt_kernel<<<(OUT_F * IN_F) / 256, 256, 0, stream>>>(W, Wt);
    gemm_mfma_kernel<<<(N_NODES + 127) / 128, 256, 0, stream>>>(x, Wt, support);

    bhist_kernel<<<NCHB, 256, 0, stream>>>(erow, bcnt);
    bscan_kernel<<<1, 1024, 0, stream>>>(bcnt, boffs, bcur);
    bscatter_kernel<<<NCHB, 256, 0, stream>>>(erow, ecol, eval, bcur, ebuf);

    bspmm_kernel<<<NBUCK * 2, 256, 0, stream>>>(boffs, ebuf, support, bias, out);
}